// Round 4
// baseline (131.336 us; speedup 1.0000x reference)
//
#include <hip/hip_runtime.h>
#include <hip/hip_bf16.h>
#include <stdint.h>

typedef __attribute__((ext_vector_type(8))) __bf16 bf16x8;
typedef __attribute__((ext_vector_type(16))) float floatx16;

#if __has_builtin(__builtin_amdgcn_exp2f)
#define EXP2F(x) __builtin_amdgcn_exp2f(x)
#else
#define EXP2F(x) exp2f(x)
#endif

#define GAS __attribute__((address_space(1)))
#define LAS __attribute__((address_space(3)))

// sqrt(2*log2(e)): baked into normalized rows so dot = 2*log2(e)*cos and
// sim = exp2(dot) = exp(cos/0.5) with zero epilogue multiplies.
#define SCALE_SQRT 1.69864359f
#define JCH 8    // j-chunks per strip; grid = 64 strips x 8 = 512 blocks (2/CU)
#define JPB 16   // j-tiles (64 cols) per block, compile-time for full unroll

// ---- sort pass 1: decode labels (int64 hedge), per-256-chunk hist + ranks ----
__global__ __launch_bounds__(256) void k_sort1(const int* __restrict__ raw,
                                               int* __restrict__ lab,
                                               int* __restrict__ ranks,
                                               int* __restrict__ cnt, int N) {
  __shared__ int h[64];
  __shared__ int s64;
  const int r = blockIdx.x * 256 + threadIdx.x;
  if (threadIdx.x < 64) {
    h[threadIdx.x] = 0;
    const int probe = raw[2 * threadIdx.x + 1];  // odd words all 0 => int64
    const unsigned long long b = __ballot(probe != 0);
    if (threadIdx.x == 0) s64 = (b == 0ull);
  }
  __syncthreads();
  const int l = (s64 ? raw[2 * r] : raw[r]) & 63;
  lab[r] = l;
  ranks[r] = atomicAdd(&h[l], 1);
  __syncthreads();
  if (threadIdx.x < 64) cnt[blockIdx.x * 64 + threadIdx.x] = h[threadIdx.x];
}

// ---- sort pass 2: scan 32x64 counts -> per-chunk bases + class cumsum -------
__global__ __launch_bounds__(256) void k_scan(const int* __restrict__ cnt,
                                              int* __restrict__ base,
                                              int* __restrict__ cum, int N) {
  __shared__ int tot[64];
  const int k = threadIdx.x;
  const int nch = N >> 8;  // 32
  if (k < 64) {
    int run = 0;
    for (int c = 0; c < nch; ++c) { base[c * 64 + k] = run; run += cnt[c * 64 + k]; }
    tot[k] = run;
  }
  __syncthreads();
  if (k == 0) {
    int run = 0;
    for (int i = 0; i < 64; ++i) { cum[i] = run; run += tot[i]; }
    cum[64] = run;
  }
  __syncthreads();
  for (int i = threadIdx.x; i < nch * 64; i += 256) base[i] += cum[i & 63];
}

// ---- prep: normalize + scale + bf16, scatter into label-sorted order --------
__global__ __launch_bounds__(256) void k_prep(const float* __restrict__ x,
                                              const int* __restrict__ lab,
                                              const int* __restrict__ ranks,
                                              const int* __restrict__ base,
                                              ushort* __restrict__ xb,
                                              int* __restrict__ labs, int N) {
  const int row = (blockIdx.x * 256 + threadIdx.x) >> 6;  // one wave per row
  const int lane = threadIdx.x & 63;
  if (row >= N) return;
  const int l = lab[row];
  const int slot = base[(row >> 8) * 64 + l] + ranks[row];
  const float2 v = ((const float2*)(x + (size_t)row * 128))[lane];
  float ss = v.x * v.x + v.y * v.y;
#pragma unroll
  for (int m = 1; m < 64; m <<= 1) ss += __shfl_xor(ss, m, 64);
  const float rn = SCALE_SQRT / fmaxf(sqrtf(ss), 1e-12f);
  __hip_bfloat162 o;
  o.x = __float2bfloat16(v.x * rn);
  o.y = __float2bfloat16(v.y * rn);
  ((__hip_bfloat162*)xb)[slot * 64 + lane] = o;
  if (lane == 0) labs[slot] = l;
}

// ---- main: full-matrix exp(x x^T/T) row sums, label-sorted ------------------
// Block: 256 thr, i-strip 128 rows, JPB j-tiles of 64 cols. A-fragments live in
// registers for the whole j-loop (loaded once from LDS); B double-buffered with
// prefetch-before-compute. Sorted labels => pos/diag handling is a uniform
// scalar branch, taken on ~1-3 of 16 tiles; plain tiles: exp2+add only.
__global__ __launch_bounds__(256, 2) void k_sim(const ushort* __restrict__ xb,
                                                const int* __restrict__ labs,
                                                const int* __restrict__ cum,
                                                float* __restrict__ pneg,
                                                float* __restrict__ ppos, int N) {
  __shared__ ushort ldsA[128 * 128];     // 32 KB
  __shared__ ushort ldsB[2][64 * 128];   // 2 x 16 KB
  const int tid = threadIdx.x;
  const int lane = tid & 63;
  const int wv = tid >> 6;
  const int wy = wv >> 1, wx = wv & 1;   // wave: rows wy*64+[0,64), cols wx*32+[0,32)
  const int l31 = lane & 31, g2 = lane >> 5;
  const int l15 = lane & 15, g4 = lane >> 4;
  const int i0 = blockIdx.y * 128;
  const int c = blockIdx.x;
  const int jt0 = c * JPB;

  // C/D 32x32 layout: col = lane&31, row = (reg&3) + 8*(reg>>2) + 4*(lane>>5)
  auto rowOff = [&](int t) -> int {
    const int reg = t & 15, mi = t >> 4;
    return wy * 64 + mi * 32 + (reg & 3) + 8 * (reg >> 2) + 4 * g2;
  };

  // ---- stage A strip (32 KB) + first B tile, XOR-16 source-permuted swizzle ----
#pragma unroll
  for (int it = 0; it < 8; ++it) {
    const int r0 = it * 16 + wv * 4;     // wave-uniform LDS row base
    const int lr = r0 + g4;
    const int kb = l15 ^ (lr & 15);
    const ushort* gp = xb + (size_t)(i0 + lr) * 128 + kb * 8;
    __builtin_amdgcn_global_load_lds((GAS void*)gp, (LAS void*)&ldsA[r0 * 128], 16, 0, 0);
  }
  {
    const int j0 = jt0 * 64;
#pragma unroll
    for (int it = 0; it < 4; ++it) {
      const int r0 = it * 16 + wv * 4;
      const int lr = r0 + g4;
      const int kb = l15 ^ (lr & 15);
      const ushort* gp = xb + (size_t)(j0 + lr) * 128 + kb * 8;
      __builtin_amdgcn_global_load_lds((GAS void*)gp, (LAS void*)&ldsB[0][r0 * 128], 16, 0, 0);
    }
  }

  // block-uniform positive column range (labels sorted => contiguous)
  const int ps = cum[labs[i0]];
  const int pe = cum[labs[i0 + 127] + 1];

  // per-lane row labels, packed 4x8b (only consulted on pos tiles)
  int li_pack[8];
#pragma unroll
  for (int q = 0; q < 8; ++q) li_pack[q] = 0;
#pragma unroll
  for (int t = 0; t < 32; ++t)
    li_pack[t >> 2] |= labs[i0 + rowOff(t)] << ((t & 3) * 8);

  float neg[32], pos[32];
#pragma unroll
  for (int t = 0; t < 32; ++t) { neg[t] = 0.0f; pos[t] = 0.0f; }

  __syncthreads();  // A + B0 staged (per-wave vmcnt drained at barrier)

  // ---- A fragments -> registers, reused across all j-tiles ----
  bf16x8 afr[2][8];
#pragma unroll
  for (int mi = 0; mi < 2; ++mi) {
    const int arow = wy * 64 + mi * 32 + l31;
#pragma unroll
    for (int kt = 0; kt < 8; ++kt) {
      const int akb = (kt * 2 + g2) ^ (arow & 15);
      afr[mi][kt] = *(const bf16x8*)&ldsA[arow * 128 + akb * 8];
    }
  }
  // B LDS addresses precomputed (ushort indices into ldsB[0])
  int baddr[8];
  {
    const int brow = wx * 32 + l31;
#pragma unroll
    for (int kt = 0; kt < 8; ++kt)
      baddr[kt] = brow * 128 + (((kt * 2 + g2) ^ (brow & 15)) * 8);
  }

#pragma unroll
  for (int t = 0; t < JPB; ++t) {
    const int j0 = (jt0 + t) * 64;
    const int buf = t & 1;
    if (t + 1 < JPB) {  // prefetch next B; lands during this tile's compute
      const int jn = j0 + 64;
#pragma unroll
      for (int it = 0; it < 4; ++it) {
        const int r0 = it * 16 + wv * 4;
        const int lr = r0 + g4;
        const int kb = l15 ^ (lr & 15);
        const ushort* gp = xb + (size_t)(jn + lr) * 128 + kb * 8;
        __builtin_amdgcn_global_load_lds((GAS void*)gp, (LAS void*)&ldsB[buf ^ 1][r0 * 128], 16, 0, 0);
      }
    }

    floatx16 acc[2];
    acc[0] = (floatx16)(0.0f);
    acc[1] = (floatx16)(0.0f);
#pragma unroll
    for (int kt = 0; kt < 8; ++kt) {
      const bf16x8 bfr = *(const bf16x8*)&ldsB[buf][baddr[kt]];
      acc[0] = __builtin_amdgcn_mfma_f32_32x32x16_bf16(afr[0][kt], bfr, acc[0], 0, 0, 0);
      acc[1] = __builtin_amdgcn_mfma_f32_32x32x16_bf16(afr[1][kt], bfr, acc[1], 0, 0, 0);
    }

    // ---- epilogue (branches are block-uniform) ----
    const bool posT = (j0 < pe) && (j0 + 64 > ps);
    if (!posT) {  // common: neg only
#pragma unroll
      for (int mi = 0; mi < 2; ++mi)
#pragma unroll
        for (int reg = 0; reg < 16; ++reg)
          neg[mi * 16 + reg] += EXP2F(acc[mi][reg]);
    } else {
      const int lj = labs[j0 + wx * 32 + l31];
      const int dlt = j0 - i0;
      const bool dg = ((unsigned)dlt < 128u);
      const int jc = wx * 32 + l31 + dlt;
      auto epi = [&](bool DG) {
#pragma unroll
        for (int mi = 0; mi < 2; ++mi) {
#pragma unroll
          for (int reg = 0; reg < 16; ++reg) {
            const int t2 = mi * 16 + reg;
            float e = EXP2F(acc[mi][reg]);
            if (DG) {
              const int ir = wy * 64 + mi * 32 + (reg & 3) + 8 * (reg >> 2) + 4 * g2;
              if (ir == jc) e = 0.0f;  // exclude self-similarity exactly
            }
            const int liq = (li_pack[t2 >> 2] >> ((t2 & 3) * 8)) & 63;
            neg[t2] += e;
            pos[t2] += (liq == lj) ? e : 0.0f;
          }
        }
      };
      if (dg) epi(true); else epi(false);
    }
    __syncthreads();  // buf reads done; prefetch(t+1) drained at this barrier
  }

  // ---- flush: wave-reduce 32 cols, combine wx halves in LDS, plain stores ----
  float* fl = (float*)ldsB;  // [row][neg|pos][wx]
#pragma unroll
  for (int t = 0; t < 32; ++t) {
    float n = neg[t], p = pos[t];
#pragma unroll
    for (int m = 1; m < 32; m <<= 1) {
      n += __shfl_xor(n, m, 64);
      p += __shfl_xor(p, m, 64);
    }
    if (l31 == 0) {
      const int r = rowOff(t);
      fl[(r * 2 + 0) * 2 + wx] = n;
      fl[(r * 2 + 1) * 2 + wx] = p;
    }
  }
  __syncthreads();
  if (tid < 128) {
    const int r = tid;
    pneg[(size_t)c * N + i0 + r] = fl[(r * 2 + 0) * 2] + fl[(r * 2 + 0) * 2 + 1];
    ppos[(size_t)c * N + i0 + r] = fl[(r * 2 + 1) * 2] + fl[(r * 2 + 1) * 2 + 1];
  }
}

// ---- finalize: sum partials + mean(log(neg*cnt/pos)) ------------------------
__global__ __launch_bounds__(1024) void k_final(const float* __restrict__ pneg,
                                                const float* __restrict__ ppos,
                                                const int* __restrict__ labs,
                                                const int* __restrict__ cum,
                                                float* __restrict__ out, int N) {
  double s = 0.0;
  for (int i = threadIdx.x; i < N; i += 1024) {
    float n = 0.0f, p = 0.0f;
#pragma unroll
    for (int c = 0; c < JCH; ++c) {
      n += pneg[(size_t)c * N + i];
      p += ppos[(size_t)c * N + i];
    }
    const int l = labs[i];
    const float cnt = (float)(cum[l + 1] - cum[l] - 1);
    s += (double)logf(n * cnt / p);
  }
#pragma unroll
  for (int m = 1; m < 64; m <<= 1) s += __shfl_xor(s, m, 64);
  __shared__ double wsum[16];
  if ((threadIdx.x & 63) == 0) wsum[threadIdx.x >> 6] = s;
  __syncthreads();
  if (threadIdx.x == 0) {
    double tot = 0.0;
    for (int w = 0; w < 16; ++w) tot += wsum[w];
    out[0] = (float)(tot / (double)N);
  }
}

extern "C" void kernel_launch(void* const* d_in, const int* in_sizes, int n_in,
                              void* d_out, int out_size, void* d_ws, size_t ws_size,
                              hipStream_t stream) {
  const float* x = (const float*)d_in[0];
  const int* raw_label = (const int*)d_in[1];
  const int N = in_sizes[1];  // 8192
  char* ws = (char*)d_ws;
  ushort* xb = (ushort*)ws;                          // N*128 bf16 = 2 MB
  float* pneg = (float*)(ws + (size_t)N * 128 * 2);  // JCH*N f32
  float* ppos = pneg + (size_t)JCH * N;              // JCH*N f32
  int* lab = (int*)(ppos + (size_t)JCH * N);         // N
  int* ranks = lab + N;                              // N
  int* labs = ranks + N;                             // N (sorted labels)
  int* cnt = labs + N;                               // (N/256)*64
  int* base = cnt + (N >> 8) * 64;                   // (N/256)*64
  int* cum = base + (N >> 8) * 64;                   // 65
  float* out = (float*)d_out;

  k_sort1<<<dim3(N / 256), dim3(256), 0, stream>>>(raw_label, lab, ranks, cnt, N);
  k_scan<<<dim3(1), dim3(256), 0, stream>>>(cnt, base, cum, N);
  k_prep<<<dim3(N / 4), dim3(256), 0, stream>>>(x, lab, ranks, base, xb, labs, N);
  k_sim<<<dim3(JCH, N / 128), dim3(256), 0, stream>>>(xb, labs, cum, pneg, ppos, N);
  k_final<<<dim3(1), dim3(1024), 0, stream>>>(pneg, ppos, labs, cum, out, N);
}